// Round 3
// baseline (264.352 us; speedup 1.0000x reference)
//
#include <hip/hip_runtime.h>

// Problem: B=2048 batches, N=64 members, D=256, H=16.
// out[b,n] = softmax_n( relu( (N*u[b,n,:] - sum_n u[b,n,:]) * item[b,:] @ W1 + b1 ) @ W2 )
// (b2 dropped: softmax is shift-invariant.)
//
// R2 lesson: the old structure spent ~19us/CU of serialized LDS-pipe time
// (576 ds_*_b128 per wave x 8 waves x ~10cy) -- co-bottleneck with the
// 21.7us HBM floor. Prefetch-depth tuning was twice-neutral because DS,
// not HBM latency, was binding.
//
// This version: NO LDS AT ALL. The reduction axis (d) is lane-local:
// lane (row0=lane>>3, col4=lane&7) owns n in {row0+8i} and d-columns
// {col4+8t} -- exactly the float4s it loads (coalesced: 8x128B segments
// per instruction). It accumulates partial y'[8n][16h] over its d-subset
// in 128 VGPRs; W1 fragments are read straight from global (16KB,
// L1/L2-resident broadcast gather); the d-reduction is a 3-round
// __shfl_xor butterfly (masks 1,2,4). DS ops: 576 -> 0. Barriers: 0.

static constexpr int NMEM  = 64;
static constexpr int DDIM  = 256;
static constexpr int NTILE = 8;    // lane's float4-column per tile: c = col4 + 8t

__device__ __forceinline__ void fma4(float4& a, float s, const float4& w) {
    a.x = fmaf(s, w.x, a.x); a.y = fmaf(s, w.y, a.y);
    a.z = fmaf(s, w.z, a.z); a.w = fmaf(s, w.w, a.w);
}
__device__ __forceinline__ float4 shfl4x(const float4& v, int m) {
    float4 r;
    r.x = __shfl_xor(v.x, m, 64); r.y = __shfl_xor(v.y, m, 64);
    r.z = __shfl_xor(v.z, m, 64); r.w = __shfl_xor(v.w, m, 64);
    return r;
}
__device__ __forceinline__ void add4(float4& a, const float4& b) {
    a.x += b.x; a.y += b.y; a.z += b.z; a.w += b.w;
}

__global__ __launch_bounds__(256, 2)
void attn_group_softmax(const float* __restrict__ u_g,     // [B,64,256]
                        const float* __restrict__ item_g,  // [B,256]
                        const float* __restrict__ W1,      // [256,16]
                        const float* __restrict__ b1,      // [16]
                        const float* __restrict__ W2,      // [16,1]
                        float* __restrict__ out)           // [B,64]
{
    const int tid  = threadIdx.x;
    const int w    = tid >> 6;                // wave id 0..3
    const int lane = tid & 63;
    const int b    = blockIdx.x * 4 + w;      // one batch per wave
    const int row0 = lane >> 3;               // owns n = row0 + 8i, i=0..7
    const int col4 = lane & 7;                // owns d-float4-col c = col4 + 8t

    const float4* ug4 = (const float4*)u_g + (size_t)b * (NMEM * DDIM / 4);
    const float4* ig4 = (const float4*)(item_g + (size_t)b * DDIM);
    const float4* w14 = (const float4*)W1;    // row d -> 4 float4 (16 h)

    // accumulators: acc[i][g] = partial y'[row0+8i][4g..4g+3] over lane's d's
    float4 acc[8][4];
    #pragma unroll
    for (int i = 0; i < 8; ++i)
        #pragma unroll
        for (int g = 0; g < 4; ++g)
            acc[i][g] = make_float4(0.f, 0.f, 0.f, 0.f);

    // 1-deep prefetch of the lane's own u-column (8 rows x 1 float4) + item
    float4 uc[8], un[8];
    #pragma unroll
    for (int i = 0; i < 8; ++i)
        uc[i] = ug4[(row0 + 8 * i) * (DDIM / 4) + col4];
    float4 itc = ig4[col4];
    float4 itn = itc;

    #pragma unroll
    for (int t = 0; t < NTILE; ++t) {
        if (t + 1 < NTILE) {
            #pragma unroll
            for (int i = 0; i < 8; ++i)
                un[i] = ug4[(row0 + 8 * i) * (DDIM / 4) + (t + 1) * 8 + col4];
            itn = ig4[(t + 1) * 8 + col4];
        }
        // W1 rows for this tile: d = 4*(col4+8t) + j, j=0..3 (256B contiguous/lane)
        const int rbase = (col4 + 8 * t) * 4;
        #pragma unroll
        for (int j = 0; j < 4; ++j) {
            const float4 wr0 = w14[(rbase + j) * 4 + 0];
            const float4 wr1 = w14[(rbase + j) * 4 + 1];
            const float4 wr2 = w14[(rbase + j) * 4 + 2];
            const float4 wr3 = w14[(rbase + j) * 4 + 3];
            const float itj = (j == 0) ? itc.x : (j == 1) ? itc.y
                            : (j == 2) ? itc.z : itc.w;
            #pragma unroll
            for (int i = 0; i < 8; ++i) {
                const float uj = (j == 0) ? uc[i].x : (j == 1) ? uc[i].y
                               : (j == 2) ? uc[i].z : uc[i].w;
                const float s = uj * itj;   // fold item at use (no extra regs)
                fma4(acc[i][0], s, wr0);
                fma4(acc[i][1], s, wr1);
                fma4(acc[i][2], s, wr2);
                fma4(acc[i][3], s, wr3);
            }
        }
        if (t + 1 < NTILE) {
            #pragma unroll
            for (int i = 0; i < 8; ++i) uc[i] = un[i];
            itc = itn;
        }
    }

    // ---- d-reduction: butterfly over the 8 col4-lanes (masks 1,2,4) ----
    // afterwards acc is the FULL y'[row0+8i][h], replicated across col4.
    #pragma unroll
    for (int m = 1; m <= 4; m <<= 1)
        #pragma unroll
        for (int i = 0; i < 8; ++i)
            #pragma unroll
            for (int g = 0; g < 4; ++g)
                add4(acc[i][g], shfl4x(acc[i][g], m));

    // ---- tt[h] = sum over all 64 n of y'[n,h] ----
    float4 tt[4];
    #pragma unroll
    for (int g = 0; g < 4; ++g) {
        tt[g] = acc[0][g];
        #pragma unroll
        for (int i = 1; i < 8; ++i) add4(tt[g], acc[i][g]);
        #pragma unroll
        for (int m = 8; m <= 32; m <<= 1) add4(tt[g], shfl4x(tt[g], m));
    }

    const float4* b14 = (const float4*)b1;
    const float4* w24 = (const float4*)W2;
    float4 bt[4], w2v[4];
    #pragma unroll
    for (int g = 0; g < 4; ++g) {
        const float4 bb = b14[g];
        bt[g]  = make_float4(bb.x - tt[g].x, bb.y - tt[g].y,
                             bb.z - tt[g].z, bb.w - tt[g].w);
        w2v[g] = w24[g];
    }

    // ---- logits for the lane's 8 n's (replicated across col4) ----
    float lp[8];
    #pragma unroll
    for (int i = 0; i < 8; ++i) {
        float p = 0.f;
        #pragma unroll
        for (int g = 0; g < 4; ++g) {
            const float zx = fmaxf(fmaf(64.f, acc[i][g].x, bt[g].x), 0.f);
            const float zy = fmaxf(fmaf(64.f, acc[i][g].y, bt[g].y), 0.f);
            const float zz = fmaxf(fmaf(64.f, acc[i][g].z, bt[g].z), 0.f);
            const float zw = fmaxf(fmaf(64.f, acc[i][g].w, bt[g].w), 0.f);
            p += zx * w2v[g].x + zy * w2v[g].y + zz * w2v[g].z + zw * w2v[g].w;
        }
        lp[i] = p;
    }

    // ---- softmax over 64 n (8 local + butterfly over row0-lanes 8,16,32) ----
    float mx = lp[0];
    #pragma unroll
    for (int i = 1; i < 8; ++i) mx = fmaxf(mx, lp[i]);
    #pragma unroll
    for (int m = 8; m <= 32; m <<= 1) mx = fmaxf(mx, __shfl_xor(mx, m, 64));
    float e[8], s = 0.f;
    #pragma unroll
    for (int i = 0; i < 8; ++i) { e[i] = __expf(lp[i] - mx); s += e[i]; }
    #pragma unroll
    for (int m = 8; m <= 32; m <<= 1) s += __shfl_xor(s, m, 64);
    const float inv = 1.0f / s;

    // lane writes n = row0 + 8*col4 -> value e[col4] (compile-time select chain,
    // avoids runtime-indexed register array -> no scratch). 64 lanes cover the
    // 256B output block of batch b in one coalesced (permuted) store.
    float ev = e[0];
    ev = (col4 == 1) ? e[1] : ev;
    ev = (col4 == 2) ? e[2] : ev;
    ev = (col4 == 3) ? e[3] : ev;
    ev = (col4 == 4) ? e[4] : ev;
    ev = (col4 == 5) ? e[5] : ev;
    ev = (col4 == 6) ? e[6] : ev;
    ev = (col4 == 7) ? e[7] : ev;
    out[(size_t)b * NMEM + row0 + 8 * col4] = ev * inv;
}

extern "C" void kernel_launch(void* const* d_in, const int* in_sizes, int n_in,
                              void* d_out, int out_size, void* d_ws, size_t ws_size,
                              hipStream_t stream) {
    const float* u    = (const float*)d_in[0];  // members_embeds [2048,64,256]
    const float* item = (const float*)d_in[1];  // item_embeds   [2048,256]
    const float* W1   = (const float*)d_in[2];  // [256,16]
    const float* b1   = (const float*)d_in[3];  // [16]
    const float* W2   = (const float*)d_in[4];  // [16,1]
    // d_in[5] = b2: dropped (softmax shift-invariant)
    (void)in_sizes; (void)n_in; (void)out_size; (void)d_ws; (void)ws_size;

    attn_group_softmax<<<512, 256, 0, stream>>>(u, item, W1, b1, W2, (float*)d_out);
}